// Round 1
// baseline (358.507 us; speedup 1.0000x reference)
//
#include <hip/hip_runtime.h>
#include <hip/hip_bf16.h>

// SegFormerXAttention: B=2, LV=1024, LT=512, D=1024, H=16, DH=64
#define NH 16

typedef __attribute__((ext_vector_type(4))) float f32x4;
typedef __attribute__((ext_vector_type(8))) __bf16 bf16x8;

__device__ __forceinline__ short f2bs(float f) {
  union { float f; unsigned u; } v; v.f = f;
  unsigned r = v.u + 0x7fffu + ((v.u >> 16) & 1u);   // RNE
  return (short)(r >> 16);
}

__device__ __forceinline__ unsigned pack2(float a, float b) {
  return ((unsigned)(unsigned short)f2bs(b) << 16) | (unsigned)(unsigned short)f2bs(a);
}

__device__ __forceinline__ f32x4 mfma16(bf16x8 a, bf16x8 b, f32x4 c) {
  return __builtin_amdgcn_mfma_f32_16x16x32_bf16(a, b, c, 0, 0, 0);
}

// ---------------- convert f32 -> bf16 ----------------
__global__ __launch_bounds__(256) void conv_kernel(const float* __restrict__ src,
                                                   short* __restrict__ dst, int n4) {
  int i = blockIdx.x * 256 + threadIdx.x;
  if (i >= n4) return;
  float4 v = *(const float4*)(src + (size_t)i * 4);
  *(uint2*)(dst + (size_t)i * 4) = make_uint2(pack2(v.x, v.y), pack2(v.z, v.w));
}

// ---------------- combined key mask [B][1536] ----------------
__global__ void kmask_kernel(const int* __restrict__ vm, const int* __restrict__ um,
                             int* __restrict__ km) {
  int i = blockIdx.x * 256 + threadIdx.x;
  if (i >= 2 * 1536) return;
  int b = i / 1536, k = i - b * 1536;
  km[i] = (k < 1024) ? vm[b * 1024 + k] : um[b * 512 + (k - 1024)];
}

// ---------------- weight transpose f32[K,N] -> bf16[N,K] ----------------
struct WPtrs { const float* s[14]; };

__global__ __launch_bounds__(256) void wtrans_kernel(WPtrs p, short* __restrict__ wt) {
  __shared__ float t[64][65];
  const float* src = p.s[blockIdx.z];
  short* dst = wt + (size_t)blockIdx.z * 1024 * 1024;
  int kb = blockIdx.y * 64, nb = blockIdx.x * 64;
  int c = threadIdx.x & 63, r0 = threadIdx.x >> 6;
  #pragma unroll
  for (int i = 0; i < 16; i++) {
    int r = r0 + i * 4;
    t[r][c] = src[(size_t)(kb + r) * 1024 + nb + c];
  }
  __syncthreads();
  #pragma unroll
  for (int i = 0; i < 16; i++) {
    int r = r0 + i * 4;
    dst[(size_t)(nb + r) * 1024 + kb + c] = f2bs(t[c][r]);
  }
}

// ---------------- 128x128 bf16 GEMM mainloop (K=1024, BK=32) ----------------
// A row-major [M,1024] bf16(short), W row-major [N,1024] bf16 (pre-transposed).
__device__ __forceinline__ void gemm_128(const short* __restrict__ X, const short* __restrict__ W,
                                         short* As, short* Bs, f32x4 (&acc)[4][4],
                                         int mb0, int nb0) {
  int tid = threadIdx.x;
  int lane = tid & 63, g = lane >> 4, r16 = lane & 15, w = tid >> 6;
  int wr = (w >> 1) * 64, wc = (w & 1) * 64;
  int lrow = tid >> 2, lcol = (tid & 3) * 8;
  for (int kt = 0; kt < 1024; kt += 32) {
    int4 va  = *(const int4*)(X + (size_t)(mb0 + lrow) * 1024 + kt + lcol);
    int4 va2 = *(const int4*)(X + (size_t)(mb0 + lrow + 64) * 1024 + kt + lcol);
    int4 vb  = *(const int4*)(W + (size_t)(nb0 + lrow) * 1024 + kt + lcol);
    int4 vb2 = *(const int4*)(W + (size_t)(nb0 + lrow + 64) * 1024 + kt + lcol);
    *(int4*)&As[lrow * 40 + lcol] = va;
    *(int4*)&As[(lrow + 64) * 40 + lcol] = va2;
    *(int4*)&Bs[lrow * 40 + lcol] = vb;
    *(int4*)&Bs[(lrow + 64) * 40 + lcol] = vb2;
    __syncthreads();
    bf16x8 af[4], bfv[4];
    #pragma unroll
    for (int i = 0; i < 4; i++) af[i]  = *(const bf16x8*)&As[(wr + i * 16 + r16) * 40 + g * 8];
    #pragma unroll
    for (int i = 0; i < 4; i++) bfv[i] = *(const bf16x8*)&Bs[(wc + i * 16 + r16) * 40 + g * 8];
    #pragma unroll
    for (int i = 0; i < 4; i++)
      #pragma unroll
      for (int j = 0; j < 4; j++)
        acc[i][j] = mfma16(af[i], bfv[j], acc[i][j]);
    __syncthreads();
  }
}

// ---------------- projection GEMMs (6 jobs per launch via blockIdx.z) ----------------
struct ProjJobs {
  const short* wt[6];
  short* dst[6];
  const float* bias[6];
  int mode[6];   // 0 = QK layout [B,H,lrows,64] (+row off), 1 = V^T layout [B,H,64,1536] (+col off)
  int lrows[6];
  int off[6];
};

__global__ __launch_bounds__(256) void proj_gemm(const short* __restrict__ X, int lqShift, ProjJobs jb) {
  __shared__ short As[128 * 40];
  __shared__ short Bs[128 * 40];
  int jz = blockIdx.z;
  int mb0 = blockIdx.y * 128, nb0 = blockIdx.x * 128;
  f32x4 acc[4][4];
  f32x4 zf = {0.f, 0.f, 0.f, 0.f};
  #pragma unroll
  for (int i = 0; i < 4; i++)
    #pragma unroll
    for (int j = 0; j < 4; j++) acc[i][j] = zf;
  gemm_128(X, jb.wt[jz], As, Bs, acc, mb0, nb0);

  int tid = threadIdx.x, lane = tid & 63, g = lane >> 4, r16 = lane & 15, w = tid >> 6;
  int wr = (w >> 1) * 64, wc = (w & 1) * 64;
  const float* bias = jb.bias[jz];
  short* dst = jb.dst[jz];
  int mode = jb.mode[jz], lrows = jb.lrows[jz], off = jb.off[jz];
  int lqMask = (1 << lqShift) - 1;
  #pragma unroll
  for (int i = 0; i < 4; i++) {
    int m0 = mb0 + wr + i * 16 + g * 4;      // 4 consecutive output rows
    #pragma unroll
    for (int j = 0; j < 4; j++) {
      int n = nb0 + wc + j * 16 + r16;
      float bv = bias[n];
      int h = n >> 6, d = n & 63;
      if (mode == 0) {
        #pragma unroll
        for (int r = 0; r < 4; r++) {
          int m = m0 + r;
          int b = m >> lqShift, l = m & lqMask;
          dst[((size_t)(b * NH + h) * lrows + off + l) * 64 + d] = f2bs(acc[i][j][r] + bv);
        }
      } else {
        int b = m0 >> lqShift, l = m0 & lqMask;   // m0 mult of 4 -> same b, consecutive l
        size_t base = ((size_t)(b * NH + h) * 64 + d) * 1536 + off + l;
        *(uint2*)(dst + base) = make_uint2(pack2(acc[i][j][0] + bv, acc[i][j][1] + bv),
                                           pack2(acc[i][j][2] + bv, acc[i][j][3] + bv));
      }
    }
  }
}

// ---------------- FF GEMM: out = A@W + bias + resid (f32 out) ----------------
__global__ __launch_bounds__(256) void ff_gemm(const short* __restrict__ A, const short* __restrict__ W,
                                               const float* __restrict__ bias, const float* __restrict__ resid,
                                               float* __restrict__ out) {
  __shared__ short As[128 * 40];
  __shared__ short Bs[128 * 40];
  int mb0 = blockIdx.y * 128, nb0 = blockIdx.x * 128;
  f32x4 acc[4][4];
  f32x4 zf = {0.f, 0.f, 0.f, 0.f};
  #pragma unroll
  for (int i = 0; i < 4; i++)
    #pragma unroll
    for (int j = 0; j < 4; j++) acc[i][j] = zf;
  gemm_128(A, W, As, Bs, acc, mb0, nb0);

  int tid = threadIdx.x, lane = tid & 63, g = lane >> 4, r16 = lane & 15, w = tid >> 6;
  int wr = (w >> 1) * 64, wc = (w & 1) * 64;
  #pragma unroll
  for (int i = 0; i < 4; i++) {
    int m0 = mb0 + wr + i * 16 + g * 4;
    #pragma unroll
    for (int j = 0; j < 4; j++) {
      int n = nb0 + wc + j * 16 + r16;
      float bv = bias[n];
      #pragma unroll
      for (int r = 0; r < 4; r++) {
        size_t idx = (size_t)(m0 + r) * 1024 + n;
        out[idx] = acc[i][j][r] + bv + resid[idx];
      }
    }
  }
}

// ---------------- fused masked attention (flash-style, swapped QK^T) ----------------
// Q: [B,H,LQ,64]; K: [B,H,1536,64]; VT: [B,H,64,1536]; out bf16 [B*LQ, 1024]
// Q switches at key 1024 (segment a: keys<1024, segment b: keys>=1024).
__global__ __launch_bounds__(256) void attn_kernel(const short* __restrict__ Qa, const short* __restrict__ Qb,
                                                   const short* __restrict__ K, const short* __restrict__ VT,
                                                   const int* __restrict__ qmask, const int* __restrict__ kmask,
                                                   short* __restrict__ out, int LQ) {
  __shared__ short P[4][16 * 40];
  const float scale = 0.125f;        // 1/sqrt(64)
  const float NEGM = -1250.0f;       // -10000 * scale (reference's where() then *scale)
  const float L2E = 1.4426950408889634f;
  int b = blockIdx.z, h = blockIdx.y, qt = blockIdx.x;
  int tid = threadIdx.x, w = tid >> 6, lane = tid & 63, g = lane >> 4, r16 = lane & 15;
  int q = qt * 64 + w * 16 + r16;
  size_t bh = (size_t)b * NH + h;

  const short* qpa = Qa + (bh * LQ + q) * 64 + g * 8;
  const short* qpb = Qb + (bh * LQ + q) * 64 + g * 8;
  bf16x8 qa0 = *(const bf16x8*)qpa;
  bf16x8 qa1 = *(const bf16x8*)(qpa + 32);
  bf16x8 qb0 = *(const bf16x8*)qpb;
  bf16x8 qb1 = *(const bf16x8*)(qpb + 32);
  int mqi = qmask[b * LQ + q];

  const short* Kb = K + bh * (size_t)(1536 * 64);
  const short* Vb = VT + bh * (size_t)(64 * 1536);
  const int* kmb = kmask + b * 1536;
  short* pw = &P[w][r16 * 40];
  const short* pr = &P[w][r16 * 40 + g * 8];

  f32x4 o[4];
  f32x4 zf = {0.f, 0.f, 0.f, 0.f};
  #pragma unroll
  for (int i = 0; i < 4; i++) o[i] = zf;
  float m_run = -1e30f, l_run = 0.f;

  for (int kb2 = 0; kb2 < 1536; kb2 += 32) {
    bf16x8 q0 = (kb2 < 1024) ? qa0 : qb0;
    bf16x8 q1 = (kb2 < 1024) ? qa1 : qb1;
    const short* k0 = Kb + (size_t)(kb2 + r16) * 64 + g * 8;
    const short* k1 = Kb + (size_t)(kb2 + 16 + r16) * 64 + g * 8;
    // S^T fragments: rows = keys, cols = q (lane owns q = r16)
    f32x4 s0 = mfma16(*(const bf16x8*)k0, q0, zf);
    s0 = mfma16(*(const bf16x8*)(k0 + 32), q1, s0);
    f32x4 s1 = mfma16(*(const bf16x8*)k1, q0, zf);
    s1 = mfma16(*(const bf16x8*)(k1 + 32), q1, s1);

    int4 km0 = *(const int4*)(kmb + kb2 + g * 4);
    int4 km1 = *(const int4*)(kmb + kb2 + 16 + g * 4);
    int kmArr[8] = {km0.x, km0.y, km0.z, km0.w, km1.x, km1.y, km1.z, km1.w};
    float sr[8] = {s0[0], s0[1], s0[2], s0[3], s1[0], s1[1], s1[2], s1[3]};
    float sv[8];
    #pragma unroll
    for (int i = 0; i < 8; i++)
      sv[i] = (mqi && kmArr[i]) ? sr[i] * scale : NEGM;

    float mloc = sv[0];
    #pragma unroll
    for (int i = 1; i < 8; i++) mloc = fmaxf(mloc, sv[i]);
    mloc = fmaxf(mloc, __shfl_xor(mloc, 16));
    mloc = fmaxf(mloc, __shfl_xor(mloc, 32));
    float m_new = fmaxf(m_run, mloc);
    float corr = exp2f((m_run - m_new) * L2E);
    float p[8];
    float ls = 0.f;
    #pragma unroll
    for (int i = 0; i < 8; i++) { p[i] = exp2f((sv[i] - m_new) * L2E); ls += p[i]; }
    ls += __shfl_xor(ls, 16);
    ls += __shfl_xor(ls, 32);
    l_run = l_run * corr + ls;
    m_run = m_new;
    #pragma unroll
    for (int i = 0; i < 4; i++) o[i] *= corr;

    // P (bf16) -> LDS [q=16][k=32] (pad 40): lane's k slots: g*4+{0..3} and 16+g*4+{0..3}
    *(unsigned*)(pw + g * 4)          = pack2(p[0], p[1]);
    *(unsigned*)(pw + g * 4 + 2)      = pack2(p[2], p[3]);
    *(unsigned*)(pw + 16 + g * 4)     = pack2(p[4], p[5]);
    *(unsigned*)(pw + 16 + g * 4 + 2) = pack2(p[6], p[7]);

    bf16x8 pb = *(const bf16x8*)pr;   // B-operand: P[q = r16][kd = g*8 + i]
    #pragma unroll
    for (int dg = 0; dg < 4; dg++) {
      const short* vr = Vb + (size_t)(dg * 16 + r16) * 1536 + kb2 + g * 8;
      o[dg] = mfma16(*(const bf16x8*)vr, pb, o[dg]);   // O^T[d, q]
    }
  }
  float inv = 1.f / l_run;
  short* ob = out + ((size_t)b * LQ + q) * 1024 + h * 64;
  #pragma unroll
  for (int dg = 0; dg < 4; dg++) {
    *(uint2*)(ob + dg * 16 + g * 4) =
        make_uint2(pack2(o[dg][0] * inv, o[dg][1] * inv), pack2(o[dg][2] * inv, o[dg][3] * inv));
  }
}

// ---------------- in-place LayerNorm over rows of 1024 ----------------
__global__ __launch_bounds__(256) void ln_kernel(float* __restrict__ y, const float* __restrict__ gam,
                                                 const float* __restrict__ bet) {
  __shared__ float sh[8];
  size_t row = blockIdx.x;
  int tid = threadIdx.x;
  float4 v = *(const float4*)(y + row * 1024 + tid * 4);
  float s = v.x + v.y + v.z + v.w;
  float ss = v.x * v.x + v.y * v.y + v.z * v.z + v.w * v.w;
  #pragma unroll
  for (int off = 32; off >= 1; off >>= 1) {
    s += __shfl_xor(s, off);
    ss += __shfl_xor(ss, off);
  }
  int w = tid >> 6;
  if ((tid & 63) == 0) { sh[w] = s; sh[4 + w] = ss; }
  __syncthreads();
  float st = sh[0] + sh[1] + sh[2] + sh[3];
  float sst = sh[4] + sh[5] + sh[6] + sh[7];
  float mu = st * (1.0f / 1024.0f);
  float var = sst * (1.0f / 1024.0f) - mu * mu;
  float rs = rsqrtf(var + 1e-12f);
  float4 gv = *(const float4*)(gam + tid * 4);
  float4 bv = *(const float4*)(bet + tid * 4);
  float4 ov;
  ov.x = (v.x - mu) * rs * gv.x + bv.x;
  ov.y = (v.y - mu) * rs * gv.y + bv.y;
  ov.z = (v.z - mu) * rs * gv.z + bv.z;
  ov.w = (v.w - mu) * rs * gv.w + bv.w;
  *(float4*)(y + row * 1024 + tid * 4) = ov;
}

extern "C" void kernel_launch(void* const* d_in, const int* in_sizes, int n_in,
                              void* d_out, int out_size, void* d_ws, size_t ws_size,
                              hipStream_t stream) {
  const float* vid_feat = (const float*)d_in[0];
  const float* usr_feat = (const float*)d_in[1];
  const int* vid_mask = (const int*)d_in[2];
  const int* usr_mask = (const int*)d_in[3];
  const float* v2v_W = (const float*)d_in[4];
  const float* v2v_b = (const float*)d_in[5];
  const float* t2v_W = (const float*)d_in[6];
  const float* t2v_b = (const float*)d_in[7];
  const float* v2t_W = (const float*)d_in[8];
  const float* v2t_b = (const float*)d_in[9];
  const float* t2t_W = (const float*)d_in[10];
  const float* t2t_b = (const float*)d_in[11];
  const float* ffu_W = (const float*)d_in[12];
  const float* ffu_b = (const float*)d_in[13];
  const float* ffv_W = (const float*)d_in[14];
  const float* ffv_b = (const float*)d_in[15];
  const float* lnu_g = (const float*)d_in[16];
  const float* lnu_b = (const float*)d_in[17];
  const float* lnv_g = (const float*)d_in[18];
  const float* lnv_b = (const float*)d_in[19];

  const size_t WM = 1024 * 1024;
  char* ws = (char*)d_ws;
  size_t off = 0;
  auto alloc = [&](size_t bytes) -> void* {
    void* p = ws + off;
    off += (bytes + 255) & ~(size_t)255;
    return p;
  };
  short* Xv  = (short*)alloc((size_t)2048 * 1024 * 2);
  short* Xu  = (short*)alloc((size_t)1024 * 1024 * 2);
  short* Wt  = (short*)alloc((size_t)14 * WM * 2);
  short* Qva = (short*)alloc((size_t)2 * NH * 1024 * 64 * 2);
  short* Qvb = (short*)alloc((size_t)2 * NH * 1024 * 64 * 2);
  short* Kv  = (short*)alloc((size_t)2 * NH * 1536 * 64 * 2);
  short* VvT = (short*)alloc((size_t)2 * NH * 64 * 1536 * 2);
  short* Qta = (short*)alloc((size_t)2 * NH * 512 * 64 * 2);
  short* Qtb = (short*)alloc((size_t)2 * NH * 512 * 64 * 2);
  short* Kt  = (short*)alloc((size_t)2 * NH * 1536 * 64 * 2);
  short* VtT = (short*)alloc((size_t)2 * NH * 64 * 1536 * 2);
  short* AOv = (short*)alloc((size_t)2048 * 1024 * 2);
  short* AOu = (short*)alloc((size_t)1024 * 1024 * 2);
  int* kmask = (int*)alloc((size_t)2 * 1536 * 4);

  // 1) convert activations
  conv_kernel<<<2048, 256, 0, stream>>>(vid_feat, Xv, 2048 * 1024 / 4);
  conv_kernel<<<1024, 256, 0, stream>>>(usr_feat, Xu, 1024 * 1024 / 4);
  kmask_kernel<<<12, 256, 0, stream>>>(vid_mask, usr_mask, kmask);

  // 2) transpose weights -> bf16 [N,K]
  WPtrs wp;
  wp.s[0] = v2v_W; wp.s[1] = v2v_W + WM; wp.s[2] = v2v_W + 2 * WM;
  wp.s[3] = t2v_W; wp.s[4] = t2v_W + WM; wp.s[5] = t2v_W + 2 * WM;
  wp.s[6] = v2t_W; wp.s[7] = v2t_W + WM; wp.s[8] = v2t_W + 2 * WM;
  wp.s[9] = t2t_W; wp.s[10] = t2t_W + WM; wp.s[11] = t2t_W + 2 * WM;
  wp.s[12] = ffu_W; wp.s[13] = ffv_W;
  wtrans_kernel<<<dim3(16, 16, 14), 256, 0, stream>>>(wp, Wt);

  // 3) projection GEMMs
  ProjJobs jv;
  jv.wt[0] = Wt + 0 * WM;  jv.dst[0] = Qva; jv.bias[0] = v2v_b;        jv.mode[0] = 0; jv.lrows[0] = 1024; jv.off[0] = 0;
  jv.wt[1] = Wt + 1 * WM;  jv.dst[1] = Kv;  jv.bias[1] = v2v_b + 1024; jv.mode[1] = 0; jv.lrows[1] = 1536; jv.off[1] = 0;
  jv.wt[2] = Wt + 2 * WM;  jv.dst[2] = VvT; jv.bias[2] = v2v_b + 2048; jv.mode[2] = 1; jv.lrows[2] = 0;    jv.off[2] = 0;
  jv.wt[3] = Wt + 3 * WM;  jv.dst[3] = Qvb; jv.bias[3] = t2v_b;        jv.mode[3] = 0; jv.lrows[3] = 1024; jv.off[3] = 0;
  jv.wt[4] = Wt + 7 * WM;  jv.dst[4] = Kt;  jv.bias[4] = v2t_b + 1024; jv.mode[4] = 0; jv.lrows[4] = 1536; jv.off[4] = 0;
  jv.wt[5] = Wt + 8 * WM;  jv.dst[5] = VtT; jv.bias[5] = v2t_b + 2048; jv.mode[5] = 1; jv.lrows[5] = 0;    jv.off[5] = 0;
  proj_gemm<<<dim3(8, 16, 6), 256, 0, stream>>>(Xv, 10, jv);

  ProjJobs ju;
  ju.wt[0] = Wt + 4 * WM;  ju.dst[0] = Kv;  ju.bias[0] = t2v_b + 1024; ju.mode[0] = 0; ju.lrows[0] = 1536; ju.off[0] = 1024;
  ju.wt[1] = Wt + 5 * WM;  ju.dst[1] = VvT; ju.bias[1] = t2v_b + 2048; ju.mode[1] = 1; ju.lrows[1] = 0;    ju.off[1] = 1024;
  ju.wt[2] = Wt + 6 * WM;  ju.dst[2] = Qta; ju.bias[2] = v2t_b;        ju.mode[2] = 0; ju.lrows[2] = 512;  ju.off[2] = 0;
  ju.wt[3] = Wt + 9 * WM;  ju.dst[3] = Qtb; ju.bias[3] = t2t_b;        ju.mode[3] = 0; ju.lrows[3] = 512;  ju.off[3] = 0;
  ju.wt[4] = Wt + 10 * WM; ju.dst[4] = Kt;  ju.bias[4] = t2t_b + 1024; ju.mode[4] = 0; ju.lrows[4] = 1536; ju.off[4] = 1024;
  ju.wt[5] = Wt + 11 * WM; ju.dst[5] = VtT; ju.bias[5] = t2t_b + 2048; ju.mode[5] = 1; ju.lrows[5] = 0;    ju.off[5] = 1024;
  proj_gemm<<<dim3(8, 8, 6), 256, 0, stream>>>(Xu, 9, ju);

  // 4) attention
  attn_kernel<<<dim3(16, NH, 2), 256, 0, stream>>>(Qva, Qvb, Kv, VvT, vid_mask, kmask, AOv, 1024);
  attn_kernel<<<dim3(8, NH, 2), 256, 0, stream>>>(Qta, Qtb, Kt, VtT, usr_mask, kmask, AOu, 512);

  // 5) FF + residual (f32 into d_out), then LayerNorm in place
  float* out_v = (float*)d_out;
  float* out_u = (float*)d_out + (size_t)2 * 1024 * 1024;
  ff_gemm<<<dim3(8, 16), 256, 0, stream>>>(AOv, Wt + 13 * WM, ffv_b, vid_feat, out_v);
  ff_gemm<<<dim3(8, 8), 256, 0, stream>>>(AOu, Wt + 12 * WM, ffu_b, usr_feat, out_u);
  ln_kernel<<<2048, 256, 0, stream>>>(out_v, lnv_g, lnv_b);
  ln_kernel<<<1024, 256, 0, stream>>>(out_u, lnu_g, lnu_b);
}

// Round 2
// 212.368 us; speedup vs baseline: 1.6881x; 1.6881x over previous
//
#include <hip/hip_runtime.h>
#include <hip/hip_bf16.h>

// SegFormerXAttention: B=2, LV=1024, LT=512, D=1024, H=16, DH=64
#define NH 16

typedef __attribute__((ext_vector_type(4))) float f32x4;
typedef __attribute__((ext_vector_type(8))) __bf16 bf16x8;

__device__ __forceinline__ short f2bs(float f) {
  union { float f; unsigned u; } v; v.f = f;
  unsigned r = v.u + 0x7fffu + ((v.u >> 16) & 1u);   // RNE
  return (short)(r >> 16);
}

__device__ __forceinline__ unsigned pack2(float a, float b) {
  return ((unsigned)(unsigned short)f2bs(b) << 16) | (unsigned)(unsigned short)f2bs(a);
}

__device__ __forceinline__ f32x4 mfma16(bf16x8 a, bf16x8 b, f32x4 c) {
  return __builtin_amdgcn_mfma_f32_16x16x32_bf16(a, b, c, 0, 0, 0);
}

// async global->LDS, 16B per lane. LDS dest = wave-uniform base + lane*16.
__device__ __forceinline__ void gload16(const void* g, void* lds) {
  __builtin_amdgcn_global_load_lds(
      (const __attribute__((address_space(1))) void*)(unsigned long long)(g),
      (__attribute__((address_space(3))) void*)(unsigned)(unsigned long long)(lds),
      16, 0, 0);
}

// ---------------- convert f32 -> bf16 ----------------
__global__ __launch_bounds__(256) void conv_kernel(const float* __restrict__ src,
                                                   short* __restrict__ dst, int n4) {
  int i = blockIdx.x * 256 + threadIdx.x;
  if (i >= n4) return;
  float4 v = *(const float4*)(src + (size_t)i * 4);
  *(uint2*)(dst + (size_t)i * 4) = make_uint2(pack2(v.x, v.y), pack2(v.z, v.w));
}

// ---------------- combined key mask [B][1536] ----------------
__global__ void kmask_kernel(const int* __restrict__ vm, const int* __restrict__ um,
                             int* __restrict__ km) {
  int i = blockIdx.x * 256 + threadIdx.x;
  if (i >= 2 * 1536) return;
  int b = i / 1536, k = i - b * 1536;
  km[i] = (k < 1024) ? vm[b * 1024 + k] : um[b * 512 + (k - 1024)];
}

// ---------------- weight transpose f32[K,N] -> bf16[N,K] ----------------
struct WPtrs { const float* s[14]; };

__global__ __launch_bounds__(256) void wtrans_kernel(WPtrs p, short* __restrict__ wt) {
  __shared__ float t[64][65];
  const float* src = p.s[blockIdx.z];
  short* dst = wt + (size_t)blockIdx.z * 1024 * 1024;
  int kb = blockIdx.y * 64, nb = blockIdx.x * 64;
  int c = threadIdx.x & 63, r0 = threadIdx.x >> 6;
  #pragma unroll
  for (int i = 0; i < 16; i++) {
    int r = r0 + i * 4;
    t[r][c] = src[(size_t)(kb + r) * 1024 + nb + c];
  }
  __syncthreads();
  #pragma unroll
  for (int i = 0; i < 16; i++) {
    int r = r0 + i * 4;
    dst[(size_t)(nb + r) * 1024 + kb + c] = f2bs(t[c][r]);
  }
}

// ---------------- GEMM staging: tile [128 rows][32 k] bf16 = 8KB, swizzled source ----------------
// LDS slot s (16B): row = s>>2, c' = s&3, holds global granule c'^(row&3).
__device__ __forceinline__ void stage_g(const short* __restrict__ src, int row0, int kt,
                                        short* buf, int tid) {
  int w = tid >> 6;
  #pragma unroll
  for (int i = 0; i < 2; i++) {
    int s = i * 256 + tid;
    int row = s >> 2, c = s & 3;
    int cs = c ^ (row & 3);
    gload16(src + (size_t)(row0 + row) * 1024 + kt + cs * 8,
            buf + (size_t)(i * 256 + w * 64) * 8);
  }
}

// ---------------- 128x128 bf16 GEMM mainloop (K=1024, BK=32, dbuf + global_load_lds) ----------------
__device__ __forceinline__ void gemm_128(const short* __restrict__ X, const short* __restrict__ W,
                                         short* As, short* Bs,   // each 2*4096 shorts
                                         f32x4 (&acc)[4][4], int mb0, int nb0) {
  int tid = threadIdx.x;
  int lane = tid & 63, g = lane >> 4, r16 = lane & 15, w = tid >> 6;
  int wr = (w >> 1) * 64, wc = (w & 1) * 64;
  int cs8 = (g ^ (r16 & 3)) * 8;    // row&3 == r16&3 for all fragment rows
  stage_g(X, mb0, 0, As, tid);
  stage_g(W, nb0, 0, Bs, tid);
  __syncthreads();
  int cur = 0;
  for (int kt = 0; kt < 1024; kt += 32) {
    if (kt + 32 < 1024) {
      stage_g(X, mb0, kt + 32, As + (cur ^ 1) * 4096, tid);
      stage_g(W, nb0, kt + 32, Bs + (cur ^ 1) * 4096, tid);
    }
    const short* a = As + cur * 4096;
    const short* bb = Bs + cur * 4096;
    bf16x8 af[4], bfv[4];
    #pragma unroll
    for (int i = 0; i < 4; i++) af[i]  = *(const bf16x8*)&a[(wr + i * 16 + r16) * 32 + cs8];
    #pragma unroll
    for (int i = 0; i < 4; i++) bfv[i] = *(const bf16x8*)&bb[(wc + i * 16 + r16) * 32 + cs8];
    #pragma unroll
    for (int i = 0; i < 4; i++)
      #pragma unroll
      for (int j = 0; j < 4; j++)
        acc[i][j] = mfma16(af[i], bfv[j], acc[i][j]);
    __syncthreads();
    cur ^= 1;
  }
}

// ---------------- projection GEMMs (6 jobs per launch via blockIdx.z) ----------------
struct ProjJobs {
  const short* wt[6];
  short* dst[6];
  const float* bias[6];
  int mode[6];   // 0 = QK layout [B,H,lrows,64] (+row off), 1 = V^T layout [B,H,64,1536] (+col off)
  int lrows[6];
  int off[6];
};

__global__ __launch_bounds__(256) void proj_gemm(const short* __restrict__ X, int lqShift, ProjJobs jb) {
  __shared__ short As[2 * 4096];
  __shared__ short Bs[2 * 4096];
  int jz = blockIdx.z;
  int mb0 = blockIdx.y * 128, nb0 = blockIdx.x * 128;
  f32x4 acc[4][4];
  f32x4 zf = {0.f, 0.f, 0.f, 0.f};
  #pragma unroll
  for (int i = 0; i < 4; i++)
    #pragma unroll
    for (int j = 0; j < 4; j++) acc[i][j] = zf;
  gemm_128(X, jb.wt[jz], As, Bs, acc, mb0, nb0);

  int tid = threadIdx.x, lane = tid & 63, g = lane >> 4, r16 = lane & 15, w = tid >> 6;
  int wr = (w >> 1) * 64, wc = (w & 1) * 64;
  const float* bias = jb.bias[jz];
  short* dst = jb.dst[jz];
  int mode = jb.mode[jz], lrows = jb.lrows[jz], off = jb.off[jz];
  int lqMask = (1 << lqShift) - 1;
  #pragma unroll
  for (int i = 0; i < 4; i++) {
    int m0 = mb0 + wr + i * 16 + g * 4;      // 4 consecutive output rows
    #pragma unroll
    for (int j = 0; j < 4; j++) {
      int n = nb0 + wc + j * 16 + r16;
      float bv = bias[n];
      int h = n >> 6, d = n & 63;
      if (mode == 0) {
        #pragma unroll
        for (int r = 0; r < 4; r++) {
          int m = m0 + r;
          int b = m >> lqShift, l = m & lqMask;
          dst[((size_t)(b * NH + h) * lrows + off + l) * 64 + d] = f2bs(acc[i][j][r] + bv);
        }
      } else {
        int b = m0 >> lqShift, l = m0 & lqMask;   // m0 mult of 4 -> same b, consecutive l
        size_t base = ((size_t)(b * NH + h) * 64 + d) * 1536 + off + l;
        *(uint2*)(dst + base) = make_uint2(pack2(acc[i][j][0] + bv, acc[i][j][1] + bv),
                                           pack2(acc[i][j][2] + bv, acc[i][j][3] + bv));
      }
    }
  }
}

// ---------------- FF GEMM: out = A@W + bias + resid (f32 out) ----------------
__global__ __launch_bounds__(256) void ff_gemm(const short* __restrict__ A, const short* __restrict__ W,
                                               const float* __restrict__ bias, const float* __restrict__ resid,
                                               float* __restrict__ out) {
  __shared__ short As[2 * 4096];
  __shared__ short Bs[2 * 4096];
  int mb0 = blockIdx.y * 128, nb0 = blockIdx.x * 128;
  f32x4 acc[4][4];
  f32x4 zf = {0.f, 0.f, 0.f, 0.f};
  #pragma unroll
  for (int i = 0; i < 4; i++)
    #pragma unroll
    for (int j = 0; j < 4; j++) acc[i][j] = zf;
  gemm_128(A, W, As, Bs, acc, mb0, nb0);

  int tid = threadIdx.x, lane = tid & 63, g = lane >> 4, r16 = lane & 15, w = tid >> 6;
  int wr = (w >> 1) * 64, wc = (w & 1) * 64;
  #pragma unroll
  for (int i = 0; i < 4; i++) {
    int m0 = mb0 + wr + i * 16 + g * 4;
    #pragma unroll
    for (int j = 0; j < 4; j++) {
      int n = nb0 + wc + j * 16 + r16;
      float bv = bias[n];
      #pragma unroll
      for (int r = 0; r < 4; r++) {
        size_t idx = (size_t)(m0 + r) * 1024 + n;
        out[idx] = acc[i][j][r] + bv + resid[idx];
      }
    }
  }
}

// ---------------- attention staging: K tile [64 keys][64 dh], V^T tile [64 dh][64 k] ----------------
// LDS slot s (16B): row = s>>3, c' = s&7, holds global granule c'^(row&7).
__device__ __forceinline__ void stage_k(const short* __restrict__ Kb, int kb, short* buf, int tid) {
  int w = tid >> 6;
  #pragma unroll
  for (int i = 0; i < 2; i++) {
    int s = i * 256 + tid;
    int row = s >> 3, c = s & 7;
    int cs = c ^ (row & 7);
    gload16(Kb + (size_t)(kb + row) * 64 + cs * 8,
            buf + (size_t)(i * 256 + w * 64) * 8);
  }
}
__device__ __forceinline__ void stage_v(const short* __restrict__ Vb, int kb, short* buf, int tid) {
  int w = tid >> 6;
  #pragma unroll
  for (int i = 0; i < 2; i++) {
    int s = i * 256 + tid;
    int row = s >> 3, c = s & 7;       // row = dh
    int cs = c ^ (row & 7);
    gload16(Vb + (size_t)row * 1536 + kb + cs * 8,
            buf + (size_t)(i * 256 + w * 64) * 8);
  }
}

// ---------------- fused masked attention (flash-style, swapped QK^T, LDS-dbuf K/V) ----------------
// Merged vid+usr: blockIdx.x < 16 -> vid tile, else usr tile (x-16).
struct AttnArgs {
  const short *Qva, *Qvb, *Kv, *VvT;
  const short *Qta, *Qtb, *Kt, *VtT;
  const int *vmask, *umask, *kmask;
  short *AOv, *AOu;
};

__global__ __launch_bounds__(256) void attn_kernel(AttnArgs A) {
  __shared__ short Ks[2][64 * 64];   // 16 KB
  __shared__ short Vs[2][64 * 64];   // 16 KB
  __shared__ short Ps[4][16 * 72];   // 9 KB (per-wave P tile, stride 72)

  const float NEGM = -1803.0f;          // masked logit in log2 domain (any uniform very-negative)
  const float SCL2E = 0.18033688f;      // (1/sqrt(64)) * log2(e)
  int b = blockIdx.z, h = blockIdx.y;
  bool isV = blockIdx.x < 16;
  int qt = isV ? blockIdx.x : (blockIdx.x - 16);
  int LQ = isV ? 1024 : 512;
  const short* Qa = isV ? A.Qva : A.Qta;
  const short* Qb = isV ? A.Qvb : A.Qtb;
  const short* K  = isV ? A.Kv  : A.Kt;
  const short* VT = isV ? A.VvT : A.VtT;
  const int* qmask = isV ? A.vmask : A.umask;
  short* out = isV ? A.AOv : A.AOu;

  int tid = threadIdx.x, w = tid >> 6, lane = tid & 63, g = lane >> 4, r16 = lane & 15;
  int q = qt * 64 + w * 16 + r16;
  size_t bh = (size_t)b * NH + h;

  const short* qpa = Qa + (bh * LQ + q) * 64 + g * 8;
  const short* qpb = Qb + (bh * LQ + q) * 64 + g * 8;
  bf16x8 qa0 = *(const bf16x8*)qpa;
  bf16x8 qa1 = *(const bf16x8*)(qpa + 32);
  bf16x8 qb0 = *(const bf16x8*)qpb;
  bf16x8 qb1 = *(const bf16x8*)(qpb + 32);
  int mqi = qmask[b * LQ + q];

  const short* Kb = K + bh * (size_t)(1536 * 64);
  const short* Vb = VT + bh * (size_t)(64 * 1536);
  const int* kmb = A.kmask + b * 1536;
  short* pw = &Ps[w][r16 * 72];
  const short* pr = &Ps[w][r16 * 72];
  int sw8 = r16 & 7;

  f32x4 o[4];
  f32x4 zf = {0.f, 0.f, 0.f, 0.f};
  #pragma unroll
  for (int i = 0; i < 4; i++) o[i] = zf;
  float m_run = -1e30f, l_run = 0.f;

  stage_k(Kb, 0, Ks[0], tid);
  stage_v(Vb, 0, Vs[0], tid);
  __syncthreads();
  int cur = 0;
  for (int kb2 = 0; kb2 < 1536; kb2 += 64) {
    if (kb2 + 64 < 1536) {
      stage_k(Kb, kb2 + 64, Ks[cur ^ 1], tid);
      stage_v(Vb, kb2 + 64, Vs[cur ^ 1], tid);
    }
    const short* Kc = Ks[cur];
    const short* Vc = Vs[cur];
    bf16x8 q0 = (kb2 < 1024) ? qa0 : qb0;
    bf16x8 q1 = (kb2 < 1024) ? qa1 : qb1;

    float sv[16];
    #pragma unroll
    for (int ko = 0; ko < 4; ko++) {
      int krow = ko * 16 + r16;
      bf16x8 k0 = *(const bf16x8*)&Kc[krow * 64 + ((g ^ sw8) * 8)];
      bf16x8 k1 = *(const bf16x8*)&Kc[krow * 64 + (((4 + g) ^ sw8) * 8)];
      f32x4 s = mfma16(k0, q0, zf);          // S^T rows = keys, cols = q (lane owns q=r16)
      s = mfma16(k1, q1, s);
      int4 km4 = *(const int4*)(kmb + kb2 + ko * 16 + g * 4);
      int kma[4] = {km4.x, km4.y, km4.z, km4.w};
      #pragma unroll
      for (int j = 0; j < 4; j++)
        sv[ko * 4 + j] = (mqi && kma[j]) ? s[j] * SCL2E : NEGM;
    }
    float mloc = sv[0];
    #pragma unroll
    for (int i = 1; i < 16; i++) mloc = fmaxf(mloc, sv[i]);
    mloc = fmaxf(mloc, __shfl_xor(mloc, 16));
    mloc = fmaxf(mloc, __shfl_xor(mloc, 32));
    float m_new = fmaxf(m_run, mloc);
    float corr = exp2f(m_run - m_new);
    float p[16];
    float ls = 0.f;
    #pragma unroll
    for (int i = 0; i < 16; i++) { p[i] = exp2f(sv[i] - m_new); ls += p[i]; }
    ls += __shfl_xor(ls, 16);
    ls += __shfl_xor(ls, 32);
    l_run = l_run * corr + ls;
    m_run = m_new;
    #pragma unroll
    for (int i = 0; i < 4; i++) o[i] *= corr;

    // P (bf16) -> LDS [q=16][k=64] stride 72: lane's keys: ko*16 + g*4 + {0..3}
    #pragma unroll
    for (int ko = 0; ko < 4; ko++) {
      *(unsigned*)(pw + ko * 16 + g * 4)     = pack2(p[ko * 4 + 0], p[ko * 4 + 1]);
      *(unsigned*)(pw + ko * 16 + g * 4 + 2) = pack2(p[ko * 4 + 2], p[ko * 4 + 3]);
    }
    // PV: O^T[d,q] += V^T[d,k] * P[q,k]
    #pragma unroll
    for (int kk = 0; kk < 2; kk++) {
      bf16x8 pb = *(const bf16x8*)(pr + kk * 32 + g * 8);
      #pragma unroll
      for (int dg = 0; dg < 4; dg++) {
        int vrow = dg * 16 + r16;
        bf16x8 vf = *(const bf16x8*)&Vc[vrow * 64 + (((kk * 4 + g) ^ sw8) * 8)];
        o[dg] = mfma16(vf, pb, o[dg]);
      }
    }
    __syncthreads();
    cur ^= 1;
  }
  float inv = 1.f / l_run;
  short* ob = out + ((size_t)b * LQ + q) * 1024 + h * 64;
  #pragma unroll
  for (int dg = 0; dg < 4; dg++) {
    *(uint2*)(ob + dg * 16 + g * 4) =
        make_uint2(pack2(o[dg][0] * inv, o[dg][1] * inv), pack2(o[dg][2] * inv, o[dg][3] * inv));
  }
}

// ---------------- in-place LayerNorm over rows of 1024 ----------------
__global__ __launch_bounds__(256) void ln_kernel(float* __restrict__ y, const float* __restrict__ gam,
                                                 const float* __restrict__ bet) {
  __shared__ float sh[8];
  size_t row = blockIdx.x;
  int tid = threadIdx.x;
  float4 v = *(const float4*)(y + row * 1024 + tid * 4);
  float s = v.x + v.y + v.z + v.w;
  float ss = v.x * v.x + v.y * v.y + v.z * v.z + v.w * v.w;
  #pragma unroll
  for (int off = 32; off >= 1; off >>= 1) {
    s += __shfl_xor(s, off);
    ss += __shfl_xor(ss, off);
  }
  int w = tid >> 6;
  if ((tid & 63) == 0) { sh[w] = s; sh[4 + w] = ss; }
  __syncthreads();
  float st = sh[0] + sh[1] + sh[2] + sh[3];
  float sst = sh[4] + sh[5] + sh[6] + sh[7];
  float mu = st * (1.0f / 1024.0f);
  float var = sst * (1.0f / 1024.0f) - mu * mu;
  float rs = rsqrtf(var + 1e-12f);
  float4 gv = *(const float4*)(gam + tid * 4);
  float4 bv = *(const float4*)(bet + tid * 4);
  float4 ov;
  ov.x = (v.x - mu) * rs * gv.x + bv.x;
  ov.y = (v.y - mu) * rs * gv.y + bv.y;
  ov.z = (v.z - mu) * rs * gv.z + bv.z;
  ov.w = (v.w - mu) * rs * gv.w + bv.w;
  *(float4*)(y + row * 1024 + tid * 4) = ov;
}

extern "C" void kernel_launch(void* const* d_in, const int* in_sizes, int n_in,
                              void* d_out, int out_size, void* d_ws, size_t ws_size,
                              hipStream_t stream) {
  const float* vid_feat = (const float*)d_in[0];
  const float* usr_feat = (const float*)d_in[1];
  const int* vid_mask = (const int*)d_in[2];
  const int* usr_mask = (const int*)d_in[3];
  const float* v2v_W = (const float*)d_in[4];
  const float* v2v_b = (const float*)d_in[5];
  const float* t2v_W = (const float*)d_in[6];
  const float* t2v_b = (const float*)d_in[7];
  const float* v2t_W = (const float*)d_in[8];
  const float* v2t_b = (const float*)d_in[9];
  const float* t2t_W = (const float*)d_in[10];
  const float* t2t_b = (const float*)d_in[11];
  const float* ffu_W = (const float*)d_in[12];
  const float* ffu_b = (const float*)d_in[13];
  const float* ffv_W = (const float*)d_in[14];
  const float* ffv_b = (const float*)d_in[15];
  const float* lnu_g = (const float*)d_in[16];
  const float* lnu_b = (const float*)d_in[17];
  const float* lnv_g = (const float*)d_in[18];
  const float* lnv_b = (const float*)d_in[19];

  const size_t WM = 1024 * 1024;
  char* ws = (char*)d_ws;
  size_t off = 0;
  auto alloc = [&](size_t bytes) -> void* {
    void* p = ws + off;
    off += (bytes + 255) & ~(size_t)255;
    return p;
  };
  short* Xv  = (short*)alloc((size_t)2048 * 1024 * 2);
  short* Xu  = (short*)alloc((size_t)1024 * 1024 * 2);
  short* Wt  = (short*)alloc((size_t)14 * WM * 2);
  short* Qva = (short*)alloc((size_t)2 * NH * 1024 * 64 * 2);
  short* Qvb = (short*)alloc((size_t)2 * NH * 1024 * 64 * 2);
  short* Kv  = (short*)alloc((size_t)2 * NH * 1536 * 64 * 2);
  short* VvT = (short*)alloc((size_t)2 * NH * 64 * 1536 * 2);
  short* Qta = (short*)alloc((size_t)2 * NH * 512 * 64 * 2);
  short* Qtb = (short*)alloc((size_t)2 * NH * 512 * 64 * 2);
  short* Kt  = (short*)alloc((size_t)2 * NH * 1536 * 64 * 2);
  short* VtT = (short*)alloc((size_t)2 * NH * 64 * 1536 * 2);
  short* AOv = (short*)alloc((size_t)2048 * 1024 * 2);
  short* AOu = (short*)alloc((size_t)1024 * 1024 * 2);
  int* kmask = (int*)alloc((size_t)2 * 1536 * 4);

  // 1) convert activations + key mask
  conv_kernel<<<2048, 256, 0, stream>>>(vid_feat, Xv, 2048 * 1024 / 4);
  conv_kernel<<<1024, 256, 0, stream>>>(usr_feat, Xu, 1024 * 1024 / 4);
  kmask_kernel<<<12, 256, 0, stream>>>(vid_mask, usr_mask, kmask);

  // 2) transpose weights -> bf16 [N,K]
  WPtrs wp;
  wp.s[0] = v2v_W; wp.s[1] = v2v_W + WM; wp.s[2] = v2v_W + 2 * WM;
  wp.s[3] = t2v_W; wp.s[4] = t2v_W + WM; wp.s[5] = t2v_W + 2 * WM;
  wp.s[6] = v2t_W; wp.s[7] = v2t_W + WM; wp.s[8] = v2t_W + 2 * WM;
  wp.s[9] = t2t_W; wp.s[10] = t2t_W + WM; wp.s[11] = t2t_W + 2 * WM;
  wp.s[12] = ffu_W; wp.s[13] = ffv_W;
  wtrans_kernel<<<dim3(16, 16, 14), 256, 0, stream>>>(wp, Wt);

  // 3) projection GEMMs
  ProjJobs jv;
  jv.wt[0] = Wt + 0 * WM;  jv.dst[0] = Qva; jv.bias[0] = v2v_b;        jv.mode[0] = 0; jv.lrows[0] = 1024; jv.off[0] = 0;
  jv.wt[1] = Wt + 1 * WM;  jv.dst[1] = Kv;  jv.bias[1] = v2v_b + 1024; jv.mode[1] = 0; jv.lrows[1] = 1536; jv.off[1] = 0;
  jv.wt[2] = Wt + 2 * WM;  jv.dst[2] = VvT; jv.bias[2] = v2v_b + 2048; jv.mode[2] = 1; jv.lrows[2] = 0;    jv.off[2] = 0;
  jv.wt[3] = Wt + 3 * WM;  jv.dst[3] = Qvb; jv.bias[3] = t2v_b;        jv.mode[3] = 0; jv.lrows[3] = 1024; jv.off[3] = 0;
  jv.wt[4] = Wt + 7 * WM;  jv.dst[4] = Kt;  jv.bias[4] = v2t_b + 1024; jv.mode[4] = 0; jv.lrows[4] = 1536; jv.off[4] = 0;
  jv.wt[5] = Wt + 8 * WM;  jv.dst[5] = VtT; jv.bias[5] = v2t_b + 2048; jv.mode[5] = 1; jv.lrows[5] = 0;    jv.off[5] = 0;
  proj_gemm<<<dim3(8, 16, 6), 256, 0, stream>>>(Xv, 10, jv);

  ProjJobs ju;
  ju.wt[0] = Wt + 4 * WM;  ju.dst[0] = Kv;  ju.bias[0] = t2v_b + 1024; ju.mode[0] = 0; ju.lrows[0] = 1536; ju.off[0] = 1024;
  ju.wt[1] = Wt + 5 * WM;  ju.dst[1] = VvT; ju.bias[1] = t2v_b + 2048; ju.mode[1] = 1; ju.lrows[1] = 0;    ju.off[1] = 1024;
  ju.wt[2] = Wt + 6 * WM;  ju.dst[2] = Qta; ju.bias[2] = v2t_b;        ju.mode[2] = 0; ju.lrows[2] = 512;  ju.off[2] = 0;
  ju.wt[3] = Wt + 9 * WM;  ju.dst[3] = Qtb; ju.bias[3] = t2t_b;        ju.mode[3] = 0; ju.lrows[3] = 512;  ju.off[3] = 0;
  ju.wt[4] = Wt + 10 * WM; ju.dst[4] = Kt;  ju.bias[4] = t2t_b + 1024; ju.mode[4] = 0; ju.lrows[4] = 1536; ju.off[4] = 1024;
  ju.wt[5] = Wt + 11 * WM; ju.dst[5] = VtT; ju.bias[5] = t2t_b + 2048; ju.mode[5] = 1; ju.lrows[5] = 0;    ju.off[5] = 1024;
  proj_gemm<<<dim3(8, 8, 6), 256, 0, stream>>>(Xu, 9, ju);

  // 4) attention (merged vid+usr)
  AttnArgs aa;
  aa.Qva = Qva; aa.Qvb = Qvb; aa.Kv = Kv; aa.VvT = VvT;
  aa.Qta = Qta; aa.Qtb = Qtb; aa.Kt = Kt; aa.VtT = VtT;
  aa.vmask = vid_mask; aa.umask = usr_mask; aa.kmask = kmask;
  aa.AOv = AOv; aa.AOu = AOu;
  attn_kernel<<<dim3(24, NH, 2), 256, 0, stream>>>(aa);

  // 5) FF + residual (f32 into d_out), then LayerNorm in place
  float* out_v = (float*)d_out;
  float* out_u = (float*)d_out + (size_t)2 * 1024 * 1024;
  ff_gemm<<<dim3(8, 16), 256, 0, stream>>>(AOv, Wt + 13 * WM, ffv_b, vid_feat, out_v);
  ff_gemm<<<dim3(8, 8), 256, 0, stream>>>(AOu, Wt + 12 * WM, ffu_b, usr_feat, out_u);
  ln_kernel<<<2048, 256, 0, stream>>>(out_v, lnv_g, lnv_b);
  ln_kernel<<<1024, 256, 0, stream>>>(out_u, lnu_g, lnu_b);
}